// Round 7
// baseline (373.034 us; speedup 1.0000x reference)
//
#include <hip/hip_runtime.h>

// Problem constants (B=4, S=4096, D_MODEL=1024, H*Dk=H*Dv=1024)
#define M_TOT 16384
#define DM    1024

typedef unsigned short ushort_t;
typedef __bf16 bf16x8 __attribute__((ext_vector_type(8)));
typedef float  f32x4  __attribute__((ext_vector_type(4)));

__device__ __forceinline__ ushort_t f32_to_bf16(float f) {
    union { float f; unsigned u; } v; v.f = f;
    unsigned u = v.u;
    return (ushort_t)((u + 0x7fffu + ((u >> 16) & 1u)) >> 16);   // RNE
}
__device__ __forceinline__ float bf16_to_f32(ushort_t h) {
    union { unsigned u; float f; } v; v.u = ((unsigned)h) << 16;
    return v.f;
}

// async global->LDS, 16B per lane; LDS dest is wave-uniform base + lane*16
__device__ __forceinline__ void gload16(const ushort_t* g, ushort_t* l) {
    __builtin_amdgcn_global_load_lds(
        (const __attribute__((address_space(1))) unsigned int*)g,
        (__attribute__((address_space(3))) unsigned int*)l,
        16, 0, 0);
}

// ---------------- fused fp32 -> bf16 conversion ----------------
// x -> xb; Wv/Wg -> wcat with 16-row interleave (v rows p*32+r, g rows p*32+16+r)
// so a 256-col GEMM tile pairs v/g 16-col fragments within one wave; Wo -> wob.
__global__ __launch_bounds__(256) void cvt_all(const float* __restrict__ x,
                                               const float* __restrict__ wv,
                                               const float* __restrict__ wg,
                                               const float* __restrict__ wo,
                                               ushort_t* __restrict__ xb,
                                               ushort_t* __restrict__ wcat,
                                               ushort_t* __restrict__ wob) {
    const long NX = (long)M_TOT * DM / 4, NW = (long)DM * DM / 4;
    long i = (long)blockIdx.x * 256 + threadIdx.x;     // float4 index
    const float* src; ushort_t* dst; long so, di;
    if (i < NX) {
        src = x; so = i; dst = xb; di = i;
    } else if (i < NX + NW) {
        long j = i - NX; src = wv; so = j;
        int row = (int)(j >> 8), c4 = (int)(j & 255);
        int orow = ((row >> 4) << 5) | (row & 15);
        dst = wcat; di = (long)orow * 256 + c4;
    } else if (i < NX + 2 * NW) {
        long j = i - NX - NW; src = wg; so = j;
        int row = (int)(j >> 8), c4 = (int)(j & 255);
        int orow = ((row >> 4) << 5) | 16 | (row & 15);
        dst = wcat; di = (long)orow * 256 + c4;
    } else {
        long j = i - NX - 2 * NW; src = wo; so = j; dst = wob; di = j;
    }
    const float4 v = ((const float4*)src)[so];
    ushort4 o;
    o.x = f32_to_bf16(v.x); o.y = f32_to_bf16(v.y);
    o.z = f32_to_bf16(v.z); o.w = f32_to_bf16(v.w);
    ((ushort4*)dst)[di] = o;
}

// ---------------- producer-consumer wave-specialized GEMM (EXPERIMENT) ----------------
// BM=BN=256, 576 threads = 8 consumer waves (2M x 4N, per-wave 128x64 via
// 16x16x32, acc[8][4]) + 1 PRODUCER wave. ZERO barriers in the K-loop:
// producer stages each 32-KB unit-slot (ring of 4) with 32 global_load_lds,
// drains vmcnt(0), publishes rdy[slot]=u+1 (LDS token). Consumers spin on a
// pre-fetched token (hidden under MFMAs), read their frags, post done[slot]
// (DS ops retire in order per wave, so the post proves the reads completed),
// then run 32 MFMA. Producer re-stages slot s for unit v only after
// done[s] >= 8*(v>>2). Wave skew is unbounded -> one wave's DS/waits overlap
// its SIMD-sibling's MFMAs (the overlap every barriered schedule r0-r6
// forbade; all pinned at 790 TF / MfmaUtil 33%).
// LDS layout, fragment indexing, epilogue identical to refcheck'd r4.
// EPI=0 epilogue: silu-gate on interleaved v/g frag pairs -> gated bf16.
__global__ __launch_bounds__(576, 1) void gemmP(
    const ushort_t* __restrict__ A,
    const ushort_t* __restrict__ Bm,
    ushort_t* __restrict__ out,
    int nbs)                          // log2(n-blocks per XCD stripe)
{
    extern __shared__ ushort_t lds[];   // 4 slots x 16384 ushorts + flags
    int* flags = (int*)(lds + 65536);   // [0..3]=rdy tokens, [4..7]=done counts

    const int flat = blockIdx.x;
    const int xcd  = flat & 7;
    const int ii   = flat >> 3;
    const int m0   = ((xcd << 3) + (ii >> nbs)) << 8;
    const int n0   = (ii & ((1 << nbs) - 1)) << 8;

    const int tid  = threadIdx.x;
    const int w    = tid >> 6;         // wave 0..8 (8 = producer)
    const int l    = tid & 63;
    const int NU   = 32;

    if (tid < 8) flags[tid] = 0;
    __syncthreads();                    // the ONLY block-wide barrier

    if (w == 8) {
        // ---------------- producer wave ----------------
        // instr t in [0,16): A frag t; t in [16,32): B frag t-16.
        // frag q holds rows base + (q&7)*16 + (q>>3)*128 + (l&15),
        // lane k-chunk (l>>4)*8 (identical to r4 staging layout).
        int aBase[16], bBase[16];
#pragma unroll
        for (int t = 0; t < 16; ++t) {
            const int ro = ((t & 7) << 4) + ((t >> 3) << 7) + (l & 15);
            aBase[t] = (m0 + ro) * DM + ((l >> 4) << 3);
            bBase[t] = (n0 + ro) * DM + ((l >> 4) << 3);
        }
        for (int v = 0; v < NU; ++v) {
            const int s = v & 3;
            if (v >= 4) {
                const int need = (v >> 2) << 3;
                while (__hip_atomic_load(&flags[4 + s], __ATOMIC_RELAXED,
                                         __HIP_MEMORY_SCOPE_WORKGROUP) < need)
                    __builtin_amdgcn_s_sleep(2);
            }
            const int ko = v * 32;
            ushort_t* dst = lds + s * 16384 + l * 8;
#pragma unroll
            for (int t = 0; t < 16; ++t)
                gload16(A + aBase[t] + ko, dst + t * 512);
#pragma unroll
            for (int t = 0; t < 16; ++t)
                gload16(Bm + bBase[t] + ko, dst + 8192 + t * 512);
            asm volatile("s_waitcnt vmcnt(0)" ::: "memory");   // LDS writes landed
            __hip_atomic_store(&flags[s], v + 1, __ATOMIC_RELAXED,
                               __HIP_MEMORY_SCOPE_WORKGROUP);
        }
        return;
    }

    // ---------------- consumer waves ----------------
    const int wm   = w >> 2;           // 0..1 (M)
    const int wn   = w & 3;            // 0..3 (N)
    const int fr   = l & 15;
    const int quad = l >> 4;

    f32x4 acc[8][4];
    const f32x4 vzero = {0.f, 0.f, 0.f, 0.f};
#pragma unroll
    for (int i = 0; i < 8; ++i)
#pragma unroll
        for (int j = 0; j < 4; ++j) acc[i][j] = vzero;

    const int rA = wm * 4096 + l * 8;          // + slot*16384 + i*512
    const int rB = 8192 + wn * 2048 + l * 8;   // + slot*16384 + j*512

    // wait for unit 0
    while (__hip_atomic_load(&flags[0], __ATOMIC_RELAXED,
                             __HIP_MEMORY_SCOPE_WORKGROUP) < 1)
        __builtin_amdgcn_s_sleep(1);
    __builtin_amdgcn_sched_barrier(0);

    for (int u = 0; u < NU; ++u) {
        const int s  = u & 3;
        const int sb = s * 16384;
        bf16x8 af[8], bf[4];
#pragma unroll
        for (int j = 0; j < 4; ++j) bf[j] = *(const bf16x8*)(lds + sb + rB + j * 512);
#pragma unroll
        for (int i = 0; i < 8; ++i) af[i] = *(const bf16x8*)(lds + sb + rA + i * 512);
        __builtin_amdgcn_sched_barrier(0);
        // post done: DS ops are in-order per wave -> visible add proves the
        // 12 frag reads above were serviced; producer may then re-stage.
        __hip_atomic_fetch_add(&flags[4 + s], 1, __ATOMIC_RELAXED,
                               __HIP_MEMORY_SCOPE_WORKGROUP);
        // pre-fetch next unit's token (overlaps the MFMA cluster)
        int tok = 0x7fffffff;
        if (u + 1 < NU)
            tok = __hip_atomic_load(&flags[(u + 1) & 3], __ATOMIC_RELAXED,
                                    __HIP_MEMORY_SCOPE_WORKGROUP);
        __builtin_amdgcn_sched_barrier(0);

        __builtin_amdgcn_s_setprio(1);
#pragma unroll
        for (int j = 0; j < 4; ++j)
#pragma unroll
            for (int i = 0; i < 8; ++i)
                acc[i][j] = __builtin_amdgcn_mfma_f32_16x16x32_bf16(
                    af[i], bf[j], acc[i][j], 0, 0, 0);
        __builtin_amdgcn_s_setprio(0);

        if (u + 1 < NU) {
            while (tok < u + 2) {
                __builtin_amdgcn_s_sleep(1);
                tok = __hip_atomic_load(&flags[(u + 1) & 3], __ATOMIC_RELAXED,
                                        __HIP_MEMORY_SCOPE_WORKGROUP);
            }
            __builtin_amdgcn_sched_barrier(0);
        }
    }

    // epilogue (r4, refcheck'd); C/D layout: col = lane&15, row = quad*4 + r
    // interleaved cat-cols: even frag = v, odd frag = g (same 16 v-cols)
    const int rowb = m0 + wm * 128;
    const int colb = n0 + wn * 64;
#pragma unroll
    for (int i = 0; i < 8; ++i)
#pragma unroll
        for (int jp = 0; jp < 2; ++jp) {
            const int cb   = colb + jp * 32;
            const int vcol = ((cb >> 5) << 4) + fr;
#pragma unroll
            for (int r = 0; r < 4; ++r) {
                const int row = rowb + i * 16 + quad * 4 + r;
                float v = acc[i][2 * jp][r];
                float g = acc[i][2 * jp + 1][r];
                float gate = g / (1.0f + __expf(-g));   // silu
                out[(long)row * DM + vcol] = f32_to_bf16(v * gate);
            }
        }
}

// ---------------- r4 stagger-pipelined GEMM (CONTROL, unchanged) ----------------
template<int EPI, int NU>
__global__ __launch_bounds__(512, 2) void gemmS(
    const ushort_t* __restrict__ A,
    const ushort_t* __restrict__ Bm,
    const ushort_t* __restrict__ Xb,
    ushort_t* __restrict__ out0,
    int nbs)
{
    extern __shared__ ushort_t lds[];   // 65536 ushorts = 128 KB, 4 slots x 16384

    const int flat = blockIdx.x;
    const int xcd  = flat & 7;
    const int ii   = flat >> 3;
    const int m0   = ((xcd << 3) + (ii >> nbs)) << 8;
    const int n0   = (ii & ((1 << nbs) - 1)) << 8;

    const int tid  = threadIdx.x;
    const int w    = tid >> 6;
    const int l    = tid & 63;
    const int wm   = w >> 2;
    const int wn   = w & 3;
    const int fr   = l & 15;
    const int quad = l >> 4;

    f32x4 acc[8][4];
    const f32x4 vzero = {0.f, 0.f, 0.f, 0.f};
#pragma unroll
    for (int i = 0; i < 8; ++i)
#pragma unroll
        for (int j = 0; j < 4; ++j) acc[i][j] = vzero;

    const long sA0 = (long)(m0 + w * 16 + fr) * DM + (quad << 3);
    const long sA1 = sA0 + 128 * (long)DM;
    const long sB0 = (long)(n0 + w * 16 + fr) * DM + (quad << 3);
    const long sB1 = sB0 + 128 * (long)DM;

    auto stageA = [&](int u) {
        const int d  = (u & 3) * 16384 + w * 512;
        const int ko = u * 32;
        gload16(A + sA0 + ko, lds + d);
        gload16(A + sA1 + ko, lds + d + 4096);
    };
    auto stageB = [&](int u) {
        const int d  = (u & 3) * 16384 + 8192 + w * 512;
        const int ko = u * 32;
        gload16(Bm + sB0 + ko, lds + d);
        gload16(Bm + sB1 + ko, lds + d + 4096);
    };

    const int rA = wm * 4096 + l * 8;
    const int rB = 8192 + wn * 2048 + l * 8;

    stageA(0); stageB(0);
    stageA(1); stageB(1);
    stageA(2); stageB(2);
    asm volatile("s_waitcnt vmcnt(8)" ::: "memory");
    __builtin_amdgcn_s_barrier();

    for (int u = 0; u < NU; ++u) {
        const int sb = (u & 3) * 16384;
        bf16x8 af[4], bf[4];
#pragma unroll
        for (int j = 0; j < 4; ++j) bf[j] = *(const bf16x8*)(lds + sb + rB + j * 512);
#pragma unroll
        for (int i = 0; i < 4; ++i) af[i] = *(const bf16x8*)(lds + sb + rA + i * 512);
        if (u < NU - 3) stageA(u + 3);
        __builtin_amdgcn_s_barrier();
        __builtin_amdgcn_s_setprio(1);
#pragma unroll
        for (int j = 0; j < 4; ++j)
#pragma unroll
            for (int i = 0; i < 4; ++i)
                acc[i][j] = __builtin_amdgcn_mfma_f32_16x16x32_bf16(
                    af[i], bf[j], acc[i][j], 0, 0, 0);
        __builtin_amdgcn_s_setprio(0);
        __builtin_amdgcn_s_barrier();

#pragma unroll
        for (int i = 0; i < 4; ++i) af[i] = *(const bf16x8*)(lds + sb + rA + (4 + i) * 512);
        if (u < NU - 3) stageB(u + 3);
        __builtin_amdgcn_s_barrier();
        __builtin_amdgcn_s_setprio(1);
#pragma unroll
        for (int j = 0; j < 4; ++j)
#pragma unroll
            for (int i = 0; i < 4; ++i)
                acc[4 + i][j] = __builtin_amdgcn_mfma_f32_16x16x32_bf16(
                    af[i], bf[j], acc[4 + i][j], 0, 0, 0);
        __builtin_amdgcn_s_setprio(0);
        if (u < NU - 3)       { asm volatile("s_waitcnt vmcnt(8)" ::: "memory"); }
        else if (u == NU - 3) { asm volatile("s_waitcnt vmcnt(4)" ::: "memory"); }
        else if (u == NU - 2) { asm volatile("s_waitcnt vmcnt(0)" ::: "memory"); }
        __builtin_amdgcn_sched_barrier(0);
        __builtin_amdgcn_s_barrier();
    }

    const int rowb = m0 + wm * 128;
    const int colb = n0 + wn * 64;
    if (EPI == 0) {
#pragma unroll
        for (int i = 0; i < 8; ++i)
#pragma unroll
            for (int jp = 0; jp < 2; ++jp) {
                const int cb   = colb + jp * 32;
                const int vcol = ((cb >> 5) << 4) + fr;
#pragma unroll
                for (int r = 0; r < 4; ++r) {
                    const int row = rowb + i * 16 + quad * 4 + r;
                    float v = acc[i][2 * jp][r];
                    float g = acc[i][2 * jp + 1][r];
                    float gate = g / (1.0f + __expf(-g));
                    out0[(long)row * DM + vcol] = f32_to_bf16(v * gate);
                }
            }
    } else {
#pragma unroll
        for (int i = 0; i < 8; ++i)
#pragma unroll
            for (int j = 0; j < 4; ++j) {
                const int col = colb + j * 16 + fr;
#pragma unroll
                for (int r = 0; r < 4; ++r) {
                    const int row = rowb + i * 16 + quad * 4 + r;
                    float pre = acc[i][j][r] + bf16_to_f32(Xb[(long)row * DM + col]);
                    out0[(long)row * DM + col] = f32_to_bf16(pre);
                }
            }
    }
}

// ---------------- LayerNorm over rows of 1024 ----------------
__global__ __launch_bounds__(256) void ln_rows(const ushort_t* __restrict__ pre,
                                               const float* __restrict__ gamma,
                                               const float* __restrict__ beta,
                                               float* __restrict__ out)
{
    const int row = blockIdx.x;
    const int tid = threadIdx.x;
    const int wave = tid >> 6, lane = tid & 63;

    ushort4 u = ((const ushort4*)(pre + (long)row * DM))[tid];
    float p0 = bf16_to_f32(u.x), p1 = bf16_to_f32(u.y);
    float p2 = bf16_to_f32(u.z), p3 = bf16_to_f32(u.w);

    float s  = p0 + p1 + p2 + p3;
    float ss = p0 * p0 + p1 * p1 + p2 * p2 + p3 * p3;
#pragma unroll
    for (int off = 32; off > 0; off >>= 1) {
        s  += __shfl_down(s, off);
        ss += __shfl_down(ss, off);
    }
    __shared__ float red[8];
    __shared__ float mb[2];
    if (lane == 0) { red[wave] = s; red[4 + wave] = ss; }
    __syncthreads();
    if (tid == 0) {
        float S  = red[0] + red[1] + red[2] + red[3];
        float SS = red[4] + red[5] + red[6] + red[7];
        float mean = S * (1.0f / 1024.0f);
        float var  = SS * (1.0f / 1024.0f) - mean * mean;
        mb[0] = mean;
        mb[1] = rsqrtf(var + 1e-5f);
    }
    __syncthreads();
    const float mean = mb[0], rs = mb[1];

    float4 gm = ((const float4*)gamma)[tid];
    float4 bt = ((const float4*)beta)[tid];
    float4 o;
    o.x = (p0 - mean) * rs * gm.x + bt.x;
    o.y = (p1 - mean) * rs * gm.y + bt.y;
    o.z = (p2 - mean) * rs * gm.z + bt.z;
    o.w = (p3 - mean) * rs * gm.w + bt.w;
    ((float4*)(out + (long)row * DM))[tid] = o;
}

// ---------------- launch ----------------
extern "C" void kernel_launch(void* const* d_in, const int* in_sizes, int n_in,
                              void* d_out, int out_size, void* d_ws, size_t ws_size,
                              hipStream_t stream) {
    // setup_inputs order: x, W_Q, W_K, W_V, W_g, W_alpha, W_O, ln_gamma, ln_beta
    const float* x     = (const float*)d_in[0];
    const float* WV    = (const float*)d_in[3];
    const float* WG    = (const float*)d_in[4];
    const float* WO    = (const float*)d_in[6];
    const float* gamma = (const float*)d_in[7];
    const float* beta  = (const float*)d_in[8];
    float* out = (float*)d_out;

    // ws layout: xb 32MB | gated 32MB | wcat 4MB | wob 2MB
    const size_t SZX = (size_t)M_TOT * DM * 2;        // 32 MB
    const size_t SZW = (size_t)DM * DM * 2;           // 2 MB
    char* ws = (char*)d_ws;
    ushort_t* xb    = (ushort_t*)ws;
    ushort_t* gated = (ushort_t*)(ws + SZX);
    ushort_t* wcat  = (ushort_t*)(ws + 2 * SZX);
    ushort_t* wob   = (ushort_t*)(ws + 2 * SZX + 2 * SZW);
    ushort_t* pre   = xb;  // alias: in-place residual+store in gemmS<1>

    static bool attr_set = false;
    if (!attr_set) {
        hipFuncSetAttribute((const void*)&gemmP,
                            hipFuncAttributeMaxDynamicSharedMemorySize, 131104);
        hipFuncSetAttribute((const void*)&gemmS<1, 32>,
                            hipFuncAttributeMaxDynamicSharedMemorySize, 131072);
        attr_set = true;
    }

    const int nCvt = (M_TOT * DM + 3 * DM * DM) / 4 / 256;
    cvt_all<<<nCvt, 256, 0, stream>>>(x, WV, WG, WO, xb, wcat, wob);

    // EXPERIMENT: producer-consumer V&g cat-GEMM (512 blocks, 8 n-blocks)
    gemmP<<<512, 576, 131104, stream>>>(xb, wcat, gated, 3);
    // CONTROL: r4 O-proj (256 blocks, 4 n-blocks)
    gemmS<1, 32><<<256, 512, 131072, stream>>>(gated, wob, xb, pre, 2);

    ln_rows<<<M_TOT, 256, 0, stream>>>(pre, gamma, beta, out);
}

// Round 8
// 269.476 us; speedup vs baseline: 1.3843x; 1.3843x over previous
//
#include <hip/hip_runtime.h>

// Problem constants (B=4, S=4096, D_MODEL=1024, H*Dk=H*Dv=1024)
#define M_TOT 16384
#define DM    1024

typedef unsigned short ushort_t;
typedef __bf16 bf16x8 __attribute__((ext_vector_type(8)));
typedef float  f32x4  __attribute__((ext_vector_type(4)));

__device__ __forceinline__ ushort_t f32_to_bf16(float f) {
    union { float f; unsigned u; } v; v.f = f;
    unsigned u = v.u;
    return (ushort_t)((u + 0x7fffu + ((u >> 16) & 1u)) >> 16);   // RNE
}
__device__ __forceinline__ float bf16_to_f32(ushort_t h) {
    union { unsigned u; float f; } v; v.u = ((unsigned)h) << 16;
    return v.f;
}

// async global->LDS, 16B per lane; LDS dest is wave-uniform base + lane*16
__device__ __forceinline__ void gload16(const ushort_t* g, ushort_t* l) {
    __builtin_amdgcn_global_load_lds(
        (const __attribute__((address_space(1))) unsigned int*)g,
        (__attribute__((address_space(3))) unsigned int*)l,
        16, 0, 0);
}

// ---------------- fused fp32 -> bf16 conversion, K-TILED outputs ----------------
// All GEMM operands are stored [K/32][rows][32] ("k-tiled") so that one
// K-unit's slice is a contiguous plane. Staging model (r0-r7 post-mortem):
// every kernel was staging-feed-bound at ~10 B/cyc/CU because row-major
// staging reads 64-B half-lines (K=32 slice of a 2-KB row); the other half
// of each 128-B line is consumed ~4000 cyc later -> 2x return-path waste.
// K-tiled planes make each 1-KB global_load_lds footprint contiguous
// (16 adjacent 64-B rows) -> pure 128-B requests, 100% line utilization.
// wcat keeps the 16-row v/g interleave (v rows p*32+r, g rows p*32+16+r).
__global__ __launch_bounds__(256) void cvt_all(const float* __restrict__ x,
                                               const float* __restrict__ wv,
                                               const float* __restrict__ wg,
                                               const float* __restrict__ wo,
                                               ushort_t* __restrict__ xkt,
                                               ushort_t* __restrict__ wcat,
                                               ushort_t* __restrict__ wob) {
    const long NX = (long)M_TOT * DM / 4, NW = (long)DM * DM / 4;
    long i = (long)blockIdx.x * 256 + threadIdx.x;     // float4 index
    const float* src; ushort_t* dst; long so, di;
    if (i < NX) {
        src = x; so = i;
        int row = (int)(i >> 8), col0 = (int)(i & 255) << 2;
        dst = xkt;
        di = ((long)(col0 >> 5) * M_TOT + row) * 8 + ((col0 & 31) >> 2);
    } else if (i < NX + NW) {
        long j = i - NX; src = wv; so = j;
        int row = (int)(j >> 8), col0 = (int)(j & 255) << 2;
        int orow = ((row >> 4) << 5) | (row & 15);
        dst = wcat;
        di = ((long)(col0 >> 5) * 2048 + orow) * 8 + ((col0 & 31) >> 2);
    } else if (i < NX + 2 * NW) {
        long j = i - NX - NW; src = wg; so = j;
        int row = (int)(j >> 8), col0 = (int)(j & 255) << 2;
        int orow = ((row >> 4) << 5) | 16 | (row & 15);
        dst = wcat;
        di = ((long)(col0 >> 5) * 2048 + orow) * 8 + ((col0 & 31) >> 2);
    } else {
        long j = i - NX - 2 * NW; src = wo; so = j;
        int row = (int)(j >> 8), col0 = (int)(j & 255) << 2;
        dst = wob;
        di = ((long)(col0 >> 5) * 1024 + row) * 8 + ((col0 & 31) >> 2);
    }
    const float4 v = ((const float4*)src)[so];
    ushort4 o;
    o.x = f32_to_bf16(v.x); o.y = f32_to_bf16(v.y);
    o.z = f32_to_bf16(v.z); o.w = f32_to_bf16(v.w);
    ((ushort4*)dst)[di] = o;
}

// ---------------- r4 stagger-pipelined GEMM, K-TILED operands ----------------
// BM=BN=256, 512 threads (8 waves, 2M x 4N), per-wave 128x64 via 16x16x32,
// acc[8][4]. K = 32 units of 32. LDS 128 KB = ring of 4 unit-slots (A 16KB +
// B 16KB), fragment-tiled 1KB lane-linear frags (0 bank conflicts, linear
// gload_lds dest; layout refcheck'd r1-r7). Stage-ahead 3 units, counted
// vmcnt(8) (drain 8->4->0), one barrier per 16-MFMA phase (r4 schedule,
// refcheck'd). ONLY change vs r4: operands are k-tiled [32][rows][32], so
// each staging instruction reads 1 KB CONTIGUOUS (full 128-B packets).
// NB = B k-plane rows (2048 for wcat, 1024 for wob).
// EPI=0: silu-gate on interleaved v/g frag pairs -> gated (k-tiled [32][M][32])
// EPI=1: +bf16 residual from k-tiled Xb -> pre bf16 ROW-MAJOR [M][1024]
template<int EPI, int NB>
__global__ __launch_bounds__(512, 2) void gemmS(
    const ushort_t* __restrict__ A,    // k-tiled [32][M_TOT][32]
    const ushort_t* __restrict__ Bm,   // k-tiled [32][NB][32]
    const ushort_t* __restrict__ Xb,   // k-tiled residual (EPI=1)
    ushort_t* __restrict__ out0,
    int nbs)                           // log2(n-blocks per XCD stripe)
{
    extern __shared__ ushort_t lds[];   // 65536 ushorts = 128 KB, 4 slots x 16384

    const int flat = blockIdx.x;
    const int xcd  = flat & 7;
    const int ii   = flat >> 3;
    const int m0   = ((xcd << 3) + (ii >> nbs)) << 8;
    const int n0   = (ii & ((1 << nbs) - 1)) << 8;

    const int tid  = threadIdx.x;
    const int w    = tid >> 6;         // wave 0..7
    const int l    = tid & 63;
    const int wm   = w >> 2;           // 0..1 (M)
    const int wn   = w & 3;            // 0..3 (N)
    const int fr   = l & 15;
    const int quad = l >> 4;

    f32x4 acc[8][4];
    const f32x4 vzero = {0.f, 0.f, 0.f, 0.f};
#pragma unroll
    for (int i = 0; i < 8; ++i)
#pragma unroll
        for (int j = 0; j < 4; ++j) acc[i][j] = vzero;

    // within-plane staging offsets (ushorts): wave w owns frags {w, w+8}
    // (rows base+w*16+fr and +128), lane k-chunk quad*8 of the unit's K=32.
    // Rows are 32-ushort strided in a plane -> each instruction's 64-lane
    // footprint = 16 adjacent rows x 64 B = 1 KB contiguous.
    const int sA = (m0 + w * 16 + fr) * 32 + (quad << 3);
    const int sB = (n0 + w * 16 + fr) * 32 + (quad << 3);

    auto stageA = [&](int u) {
        const int  d  = (u & 3) * 16384 + w * 512;
        const long po = (long)u * (M_TOT * 32);
        gload16(A + po + sA, lds + d);
        gload16(A + po + sA + 4096, lds + d + 4096);    // rows +128
    };
    auto stageB = [&](int u) {
        const int  d  = (u & 3) * 16384 + 8192 + w * 512;
        const long po = (long)u * (NB * 32);
        gload16(Bm + po + sB, lds + d);
        gload16(Bm + po + sB + 4096, lds + d + 4096);   // rows +128
    };

    // fragment read bases (slot-relative, ushorts) -- unchanged from r4
    const int rA = wm * 4096 + l * 8;          // + slot*16384 + i*512
    const int rB = 8192 + wn * 2048 + l * 8;   // + slot*16384 + j*512

    // prologue: units 0,1,2 in flight (12 wave-loads); unit 0 landed
    stageA(0); stageB(0);
    stageA(1); stageB(1);
    stageA(2); stageB(2);
    asm volatile("s_waitcnt vmcnt(8)" ::: "memory");
    __builtin_amdgcn_s_barrier();

    for (int u = 0; u < 32; ++u) {
        const int sb = (u & 3) * 16384;
        bf16x8 af[4], bf[4];

        // ---- phase A: frags i=0..3 x j=0..3 (reads issue, no drain) ----
#pragma unroll
        for (int j = 0; j < 4; ++j) bf[j] = *(const bf16x8*)(lds + sb + rB + j * 512);
#pragma unroll
        for (int i = 0; i < 4; ++i) af[i] = *(const bf16x8*)(lds + sb + rA + i * 512);
        if (u < 29) stageA(u + 3);
        __builtin_amdgcn_s_barrier();
        __builtin_amdgcn_s_setprio(1);
#pragma unroll
        for (int j = 0; j < 4; ++j)
#pragma unroll
            for (int i = 0; i < 4; ++i)
                acc[i][j] = __builtin_amdgcn_mfma_f32_16x16x32_bf16(
                    af[i], bf[j], acc[i][j], 0, 0, 0);
        __builtin_amdgcn_s_setprio(0);
        __builtin_amdgcn_s_barrier();

        // ---- phase B: frags i=4..7 x j=0..3 (bf reused) ----
#pragma unroll
        for (int i = 0; i < 4; ++i) af[i] = *(const bf16x8*)(lds + sb + rA + (4 + i) * 512);
        if (u < 29) stageB(u + 3);
        __builtin_amdgcn_s_barrier();
        __builtin_amdgcn_s_setprio(1);
#pragma unroll
        for (int j = 0; j < 4; ++j)
#pragma unroll
            for (int i = 0; i < 4; ++i)
                acc[4 + i][j] = __builtin_amdgcn_mfma_f32_16x16x32_bf16(
                    af[i], bf[j], acc[4 + i][j], 0, 0, 0);
        __builtin_amdgcn_s_setprio(0);
        // counted vmcnt: guarantee unit u+1 landed before its reads issue
        if (u < 29)       { asm volatile("s_waitcnt vmcnt(8)" ::: "memory"); }
        else if (u == 29) { asm volatile("s_waitcnt vmcnt(4)" ::: "memory"); }
        else if (u == 30) { asm volatile("s_waitcnt vmcnt(0)" ::: "memory"); }
        __builtin_amdgcn_sched_barrier(0);   // pin unit-u reads before slot reuse
        __builtin_amdgcn_s_barrier();
    }

    // epilogue; C/D layout: col = lane&15, row = quad*4 + r (refcheck'd r1-r7)
    const int rowb = m0 + wm * 128;
    const int colb = n0 + wn * 64;
    if (EPI == 0) {
        // interleaved cat-cols: even frag = v, odd frag = g (same 16 v-cols);
        // write gated K-TILED: plane vcol>>5, within-chunk vcol&31.
#pragma unroll
        for (int i = 0; i < 8; ++i)
#pragma unroll
            for (int jp = 0; jp < 2; ++jp) {
                const int cb   = colb + jp * 32;
                const int vcol = ((cb >> 5) << 4) + fr;
                const long kbase = ((long)(vcol >> 5) * M_TOT) * 32 + (vcol & 31);
#pragma unroll
                for (int r = 0; r < 4; ++r) {
                    const int row = rowb + i * 16 + quad * 4 + r;
                    float v = acc[i][2 * jp][r];
                    float g = acc[i][2 * jp + 1][r];
                    float gate = g / (1.0f + __expf(-g));   // silu
                    out0[kbase + (long)row * 32] = f32_to_bf16(v * gate);
                }
            }
    } else {
        // residual from k-tiled Xb; output pre ROW-MAJOR for ln_rows
#pragma unroll
        for (int i = 0; i < 8; ++i)
#pragma unroll
            for (int j = 0; j < 4; ++j) {
                const int col = colb + j * 16 + fr;
                const long xbase = ((long)(col >> 5) * M_TOT) * 32 + (col & 31);
#pragma unroll
                for (int r = 0; r < 4; ++r) {
                    const int row = rowb + i * 16 + quad * 4 + r;
                    float pre = acc[i][j][r] + bf16_to_f32(Xb[xbase + (long)row * 32]);
                    out0[(long)row * DM + col] = f32_to_bf16(pre);
                }
            }
    }
}

// ---------------- LayerNorm over rows of 1024 ----------------
__global__ __launch_bounds__(256) void ln_rows(const ushort_t* __restrict__ pre,
                                               const float* __restrict__ gamma,
                                               const float* __restrict__ beta,
                                               float* __restrict__ out)
{
    const int row = blockIdx.x;
    const int tid = threadIdx.x;
    const int wave = tid >> 6, lane = tid & 63;

    ushort4 u = ((const ushort4*)(pre + (long)row * DM))[tid];
    float p0 = bf16_to_f32(u.x), p1 = bf16_to_f32(u.y);
    float p2 = bf16_to_f32(u.z), p3 = bf16_to_f32(u.w);

    float s  = p0 + p1 + p2 + p3;
    float ss = p0 * p0 + p1 * p1 + p2 * p2 + p3 * p3;
#pragma unroll
    for (int off = 32; off > 0; off >>= 1) {
        s  += __shfl_down(s, off);
        ss += __shfl_down(ss, off);
    }
    __shared__ float red[8];
    __shared__ float mb[2];
    if (lane == 0) { red[wave] = s; red[4 + wave] = ss; }
    __syncthreads();
    if (tid == 0) {
        float S  = red[0] + red[1] + red[2] + red[3];
        float SS = red[4] + red[5] + red[6] + red[7];
        float mean = S * (1.0f / 1024.0f);
        float var  = SS * (1.0f / 1024.0f) - mean * mean;
        mb[0] = mean;
        mb[1] = rsqrtf(var + 1e-5f);
    }
    __syncthreads();
    const float mean = mb[0], rs = mb[1];

    float4 gm = ((const float4*)gamma)[tid];
    float4 bt = ((const float4*)beta)[tid];
    float4 o;
    o.x = (p0 - mean) * rs * gm.x + bt.x;
    o.y = (p1 - mean) * rs * gm.y + bt.y;
    o.z = (p2 - mean) * rs * gm.z + bt.z;
    o.w = (p3 - mean) * rs * gm.w + bt.w;
    ((float4*)(out + (long)row * DM))[tid] = o;
}

// ---------------- launch ----------------
extern "C" void kernel_launch(void* const* d_in, const int* in_sizes, int n_in,
                              void* d_out, int out_size, void* d_ws, size_t ws_size,
                              hipStream_t stream) {
    // setup_inputs order: x, W_Q, W_K, W_V, W_g, W_alpha, W_O, ln_gamma, ln_beta
    const float* x     = (const float*)d_in[0];
    const float* WV    = (const float*)d_in[3];
    const float* WG    = (const float*)d_in[4];
    const float* WO    = (const float*)d_in[6];
    const float* gamma = (const float*)d_in[7];
    const float* beta  = (const float*)d_in[8];
    float* out = (float*)d_out;

    // ws layout: xkt 32MB | gated 32MB | wcat 4MB | wob 2MB | pre 32MB
    // (r5 ran its 134-MB split-K path, so ws_size >= 134 MB; we need 102.)
    const size_t SZX = (size_t)M_TOT * DM * 2;        // 32 MB
    const size_t SZW = (size_t)DM * DM * 2;           // 2 MB
    char* ws = (char*)d_ws;
    ushort_t* xkt   = (ushort_t*)ws;
    ushort_t* gated = (ushort_t*)(ws + SZX);
    ushort_t* wcat  = (ushort_t*)(ws + 2 * SZX);
    ushort_t* wob   = (ushort_t*)(ws + 2 * SZX + 2 * SZW);
    ushort_t* pre   = (ushort_t*)(ws + 2 * SZX + 3 * SZW);

    static bool attr_set = false;
    if (!attr_set) {
        hipFuncSetAttribute((const void*)&gemmS<0, 2048>,
                            hipFuncAttributeMaxDynamicSharedMemorySize, 131072);
        hipFuncSetAttribute((const void*)&gemmS<1, 1024>,
                            hipFuncAttributeMaxDynamicSharedMemorySize, 131072);
        attr_set = true;
    }

    const int nCvt = (M_TOT * DM + 3 * DM * DM) / 4 / 256;
    cvt_all<<<nCvt, 256, 0, stream>>>(x, WV, WG, WO, xkt, wcat, wob);

    // V&g cat-GEMM: M=16384 (64 m-blocks), N_cat=2048 (8 n-blocks) -> 512
    gemmS<0, 2048><<<512, 512, 131072, stream>>>(xkt, wcat, nullptr, gated, 3);
    // O-proj: M=16384 (64), N=1024 (4 n-blocks) -> 256
    gemmS<1, 1024><<<256, 512, 131072, stream>>>(gated, wob, xkt, pre, 2);

    ln_rows<<<M_TOT, 256, 0, stream>>>(pre, gamma, beta, out);
}